// Round 9
// baseline (864.587 us; speedup 1.0000x reference)
//
#include <hip/hip_runtime.h>
#include <hip/hip_bf16.h>

// MoE router: logits = x @ W^T, softmax, top-2, aux loss. fp32 throughout.
// T=32768, D=2048, E=64, K=2.
// Structure: lane=token (64 tok/block), 8 waves, wave w owns experts [8w,8w+8).
//   -> 16 waves/CU = 4 waves/SIMD: covers s_load (W) latency even worst-case.
//   x: global -> reg prefetch -> double-buffered LDS (1 barrier/chunk)
//   W: wave-uniform s_load -> SGPR-operand v_fmac (scalar pipe; no vector VMEM)
// d_out (float): [0..T*2) top_w, [T*2..T*4) top_idx (as float), [T*4] aux_loss.
// d_ws: 129 dwords: gcnt[64] | gsum[64] | done-counter.

constexpr int T    = 32768;
constexpr int D    = 2048;
constexpr int E    = 64;
constexpr int TPB  = 512;        // 8 waves
constexpr int EPW  = 8;          // experts per wave
constexpr int TOKB = 64;         // tokens per block (= wave width)
constexpr int DCH  = 64;         // d-chunk staged in LDS
constexpr int NCH  = D / DCH;    // 32
constexpr int XSTR = 68;         // dword stride of x rows in LDS (17 x 16B slots)

__global__ void zero_ws_kernel(float* ws) {
    if (threadIdx.x < 2 * E + 1) ws[threadIdx.x] = 0.0f;  // gcnt|gsum|done
}

__global__ __launch_bounds__(TPB, 4)   // 4 waves/EU -> VGPR cap 128 (live set ~100)
void router_kernel(const float* __restrict__ x, const float* __restrict__ W,
                   float* __restrict__ out, float* __restrict__ gcnt,
                   float* __restrict__ gsum, unsigned* __restrict__ dcnt) {
    __shared__ __align__(16) float xs[2][TOKB * XSTR];  // ping-pong x chunks
    __shared__ float lgs[TOKB * (E + 1)];               // [token][expert], pad 65
    __shared__ float cnt[E], sm[E];
    __shared__ unsigned sLast;

    const int tid   = threadIdx.x;
    const int lane  = tid & 63;
    const int wid_v = tid >> 6;
    const int wid   = __builtin_amdgcn_readfirstlane(wid_v);  // uniform wave id
    const int tok0  = blockIdx.x * TOKB;

    if (tid < E) { cnt[tid] = 0.0f; sm[tid] = 0.0f; }

    // staging: wave w stages token rows [8w, 8w+8); lane covers 2 x float4:
    //   row = 8w + (lane>>3), dword col = (lane&7)*4 + i*32  (i = 0,1)
    //   -> per instruction: 8 lanes x 16B contiguous per row (coalesced),
    //      LDS slot residues uniform mod 8 (data-volume floor, no conflicts)
    const int srow = wid * 8 + (lane >> 3);
    const int scol = (lane & 7) * 4;
    const float* xrow  = x + (size_t)(tok0 + srow) * D;
    const float* wbase = W + (size_t)wid * EPW * D;   // uniform -> s_load path

    float acc[EPW] = {};
    float4 gx[2];
    #pragma unroll
    for (int i = 0; i < 2; ++i)                        // prefetch chunk 0
        gx[i] = *(const float4*)&xrow[scol + i * 32];
    #pragma unroll
    for (int i = 0; i < 2; ++i)                        // stage chunk 0 -> buf 0
        *(float4*)&xs[0][srow * XSTR + scol + i * 32] = gx[i];
    __syncthreads();

    for (int c = 0; c < NCH; ++c) {
        const int cur = c & 1;
        if (c + 1 < NCH) {                             // prefetch next chunk
            const float* xn = xrow + (size_t)(c + 1) * DCH;
            #pragma unroll
            for (int i = 0; i < 2; ++i)
                gx[i] = *(const float4*)&xn[scol + i * 32];
        }
        // this lane's token row for the chunk: 16 balanced ds_read_b128
        float4 xf[16];
        #pragma unroll
        for (int q = 0; q < 16; ++q)
            xf[q] = *(const float4*)&xs[cur][lane * XSTR + q * 4];
        // 8 experts x 64 d FMAs; W via wave-uniform scalar loads.
        // Full unroll of e => 8 independent acc chains (hides FMA latency).
        const float* wc = wbase + (size_t)c * DCH;
        #pragma unroll
        for (int e = 0; e < EPW; ++e) {
            const float* we = wc + (size_t)e * D;
            float a = acc[e];
            #pragma unroll
            for (int q = 0; q < 16; ++q) {
                const float4 xq = xf[q];
                a = fmaf(we[q * 4 + 0], xq.x, a);
                a = fmaf(we[q * 4 + 1], xq.y, a);
                a = fmaf(we[q * 4 + 2], xq.z, a);
                a = fmaf(we[q * 4 + 3], xq.w, a);
            }
            acc[e] = a;
        }
        // stage next chunk into the other buffer (safe: that buffer's readers
        // finished before the barrier that ended iter c-1), single barrier/chunk
        if (c + 1 < NCH) {
            #pragma unroll
            for (int i = 0; i < 2; ++i)
                *(float4*)&xs[cur ^ 1][srow * XSTR + scol + i * 32] = gx[i];
        }
        __syncthreads();
    }

    // logits tile -> LDS: token=lane, experts [wid*8, +8)
    #pragma unroll
    for (int e = 0; e < EPW; ++e)
        lgs[lane * (E + 1) + wid * EPW + e] = acc[e];
    __syncthreads();

    // wave 0: per-token softmax + top-2 + outputs + aux partials
    if (wid_v == 0) {
        const float* row = &lgs[lane * (E + 1)];
        float v1 = -3.402823466e+38f, v2 = -3.402823466e+38f;
        int i1 = 0, i2 = 0;
        #pragma unroll
        for (int e = 0; e < E; ++e) {
            const float l = row[e];
            if (l > v1)      { v2 = v1; i2 = i1; v1 = l; i1 = e; }
            else if (l > v2) { v2 = l; i2 = e; }
        }
        float Z = 0.0f;
        #pragma unroll
        for (int e = 0; e < E; ++e) Z += expf(row[e] - v1);
        const float p1 = 1.0f / Z;              // top_vals[0] (unnormalized)
        const float p2 = expf(v2 - v1) / Z;     // top_vals[1]
        const float wden = p1 + p2 + 1e-9f;

        const size_t t = (size_t)(tok0 + lane);
        out[t * 2 + 0] = p1 / wden;
        out[t * 2 + 1] = p2 / wden;
        out[(size_t)T * 2 + t * 2 + 0] = (float)i1;
        out[(size_t)T * 2 + t * 2 + 1] = (float)i2;

        atomicAdd(&cnt[i1], 1.0f);  atomicAdd(&sm[i1], p1);
        atomicAdd(&cnt[i2], 1.0f);  atomicAdd(&sm[i2], p2);
    }
    __syncthreads();
    if (tid < E) {
        atomicAdd(&gcnt[tid], cnt[tid]);   // device-scope (G12)
        atomicAdd(&gsum[tid], sm[tid]);
    }
    __syncthreads();   // every thread drained its atomics before done-bump

    // last-finishing block computes the aux loss inline (saves a launch)
    if (tid == 0) {
        __threadfence();
        const unsigned v = atomicAdd(dcnt, 1u);
        sLast = (v == (unsigned)(gridDim.x - 1)) ? 1u : 0u;
    }
    __syncthreads();
    if (sLast != 0u && tid < E) {
        const float cv = atomicAdd(&gcnt[tid], 0.0f);   // coherent RMW read
        const float sv = atomicAdd(&gsum[tid], 0.0f);
        const float frac = cv / ((float)(2 * T) + 1e-6f);
        const float avg  = sv / fmaxf(cv, 1e-6f);
        float term = frac * avg;
        #pragma unroll
        for (int off = 32; off > 0; off >>= 1)
            term += __shfl_down(term, off);
        if (tid == 0) out[(size_t)T * 4] = term * (float)E;
    }
}

extern "C" void kernel_launch(void* const* d_in, const int* in_sizes, int n_in,
                              void* d_out, int out_size, void* d_ws, size_t ws_size,
                              hipStream_t stream) {
    const float* x = (const float*)d_in[0];
    const float* W = (const float*)d_in[1];
    float* out  = (float*)d_out;
    float* gcnt = (float*)d_ws;                 // 64 floats
    float* gsum = gcnt + E;                     // 64 floats
    unsigned* dcnt = (unsigned*)(gsum + E);     // 1 dword done-counter

    zero_ws_kernel<<<1, 256, 0, stream>>>((float*)d_ws);
    router_kernel<<<T / TOKB, TPB, 0, stream>>>(x, W, out, gcnt, gsum, dcnt);
}

// Round 11
// 391.545 us; speedup vs baseline: 2.2081x; 2.2081x over previous
//
#include <hip/hip_runtime.h>
#include <hip/hip_bf16.h>

// MoE router via split-fp16 MFMA: x = x0 + x1 (RN split, lo scaled 2^11),
// logits = x0·W0 + 2^-11·(x0·W1s + x1s·W0)  [x1·w1 dropped, ~2^-24 rel err].
// Expert/token labels SELF-CALIBRATED via probe MFMAs (immune to frag-layout
// assumptions). Softmax + top-2 + aux fused, all-in-register epilogue.
// T=32768, D=2048, E=64, K=2. Block: 256 thr = 4 waves, 64 tokens.
// d_out (float): [0..T*2) top_w, [T*2..T*4) top_idx (as float), [T*4] aux_loss.
// d_ws: 129 dwords: gcnt[64] | gsum[64] | done-counter.

constexpr int T    = 32768;
constexpr int D    = 2048;
constexpr int E    = 64;
constexpr int TPB  = 256;      // 4 waves
constexpr int TOKB = 64;       // tokens per block
constexpr int KC   = 64;       // d per chunk
constexpr int NCH  = D / KC;   // 32
constexpr int LSTR = 72;       // ushort stride per LDS tile row (144 B, 16B-aligned)

typedef __attribute__((ext_vector_type(8))) _Float16 half8v;  // A/B frag (4 VGPR)
typedef __attribute__((ext_vector_type(4))) float    f32x4;   // C/D frag

__global__ void zero_ws_kernel(float* ws) {
    if (threadIdx.x < 2 * E + 1) ws[threadIdx.x] = 0.0f;  // gcnt|gsum|done
}

// RN fp16 split of a,b; lo parts scaled by 2^11 (keeps them in normal f16 range)
__device__ __forceinline__ void cvt2h(float a, float b, unsigned& hi, unsigned& lo) {
    const _Float16 ah = (_Float16)a, bh = (_Float16)b;       // RN casts
    const float ar = (a - (float)ah) * 2048.0f;              // exact (Sterbenz), x2^11
    const float br = (b - (float)bh) * 2048.0f;
    const _Float16 al = (_Float16)ar, bl = (_Float16)br;
    hi = (unsigned)__builtin_bit_cast(unsigned short, ah)
       | ((unsigned)__builtin_bit_cast(unsigned short, bh) << 16);
    lo = (unsigned)__builtin_bit_cast(unsigned short, al)
       | ((unsigned)__builtin_bit_cast(unsigned short, bl) << 16);
}

// convert 16 fp32 (one row segment) into hi/lo f16 tiles at ushort offset wofs
__device__ __forceinline__ void cvt_store(const float4 g[4],
                                          unsigned short* hiT, unsigned short* loT, int wofs) {
    unsigned h[8], l[8];
    #pragma unroll
    for (int j = 0; j < 8; ++j) {
        const float a = (j & 1) ? g[j >> 1].z : g[j >> 1].x;
        const float b = (j & 1) ? g[j >> 1].w : g[j >> 1].y;
        cvt2h(a, b, h[j], l[j]);
    }
    uint4* hp = (uint4*)(hiT + wofs);
    hp[0] = make_uint4(h[0], h[1], h[2], h[3]);
    hp[1] = make_uint4(h[4], h[5], h[6], h[7]);
    uint4* lp = (uint4*)(loT + wofs);
    lp[0] = make_uint4(l[0], l[1], l[2], l[3]);
    lp[1] = make_uint4(l[4], l[5], l[6], l[7]);
}

__global__ __launch_bounds__(TPB, 2)   // 73.7 KB LDS -> 2 blocks/CU; VGPR cap 256
void router_kernel(const float* __restrict__ x, const float* __restrict__ W,
                   float* __restrict__ out, float* __restrict__ gcnt,
                   float* __restrict__ gsum, unsigned* __restrict__ dcnt) {
    // tiles: 0=x0 1=x1s 2=W0 3=W1s, double-buffered. 2*4*64*72*2B = 73728 B.
    __shared__ __align__(16) unsigned short bfT[2][4][TOKB * LSTR];
    __shared__ float cnt[E], sm[E];
    __shared__ unsigned sLast;

    const int tid  = threadIdx.x;
    const int lane = tid & 63;
    const int wid  = tid >> 6;       // wave id 0..3
    const int l15  = lane & 15;
    const int tok0 = blockIdx.x * TOKB;

    if (tid < E) { cnt[tid] = 0.0f; sm[tid] = 0.0f; }

    // staging: thread covers one row (token AND expert-row), 16 d-columns
    const int srow = tid >> 2;             // 0..63
    const int sc   = (tid & 3) << 4;       // 0,16,32,48
    const float* xsrc = x + (size_t)(tok0 + srow) * D + sc;
    const float* wsrc = W + (size_t)srow * D + sc;
    const int wofs = srow * LSTR + sc;

    float4 gx[4], gw[4];
    #pragma unroll
    for (int i = 0; i < 4; ++i) {          // stage chunk 0
        gx[i] = *(const float4*)(xsrc + i * 4);
        gw[i] = *(const float4*)(wsrc + i * 4);
    }
    cvt_store(gx, bfT[0][0], bfT[0][1], wofs);
    cvt_store(gw, bfT[0][2], bfT[0][3], wofs);
    __syncthreads();

    f32x4 acc_hh[4] = {};                  // x0·W0
    f32x4 acc_mx[4] = {};                  // 2^11·(x0·W1 + x1·W0)
    const int arow = wid * 16 + l15;       // A-tile row this lane loads
    const int kl   = (lane >> 4) * 8;      // frag k-offset within K=32

    for (int c = 0; c < NCH; ++c) {
        const int cur = c & 1;
        if (c + 1 < NCH) {                 // prefetch next chunk (hides HBM latency)
            const float* xn = xsrc + (c + 1) * KC;
            const float* wn = wsrc + (c + 1) * KC;
            #pragma unroll
            for (int i = 0; i < 4; ++i) {
                gx[i] = *(const float4*)(xn + i * 4);
                gw[i] = *(const float4*)(wn + i * 4);
            }
        }
        const unsigned short* xh = bfT[cur][0];
        const unsigned short* xl = bfT[cur][1];
        const unsigned short* wh = bfT[cur][2];
        const unsigned short* wl = bfT[cur][3];
        #pragma unroll
        for (int ks = 0; ks < 2; ++ks) {   // 2 K-steps of 32 per chunk
            const int ko = ks * 32 + kl;
            const half8v a0 = *(const half8v*)&xh[arow * LSTR + ko];
            const half8v a1 = *(const half8v*)&xl[arow * LSTR + ko];
            #pragma unroll
            for (int et = 0; et < 4; ++et) {
                const int bofs = (et * 16 + l15) * LSTR + ko;
                const half8v b0 = *(const half8v*)&wh[bofs];
                const half8v b1 = *(const half8v*)&wl[bofs];
                acc_hh[et] = __builtin_amdgcn_mfma_f32_16x16x32_f16(a0, b0, acc_hh[et], 0, 0, 0);
                acc_mx[et] = __builtin_amdgcn_mfma_f32_16x16x32_f16(a0, b1, acc_mx[et], 0, 0, 0);
                acc_mx[et] = __builtin_amdgcn_mfma_f32_16x16x32_f16(a1, b0, acc_mx[et], 0, 0, 0);
            }
        }
        if (c + 1 < NCH) {                 // write next chunk into the other buffer
            const int nb = cur ^ 1;
            cvt_store(gx, bfT[nb][0], bfT[nb][1], wofs);
            cvt_store(gw, bfT[nb][2], bfT[nb][3], wofs);
        }
        __syncthreads();
    }

    // ---- self-calibration probes: measure the REAL output labeling ----
    // col probe: A=ones, B elems = l15 (uniform over k) -> D[m][n] = 32*(l15 of col n)
    // row probe: A elems = l15, B=ones -> D[m][n] = 32*(l15 of row m), row=f(reg r)
    half8v ones8, lv8;
    #pragma unroll
    for (int j = 0; j < 8; ++j) { ones8[j] = (_Float16)1.0f; lv8[j] = (_Float16)(float)l15; }
    f32x4 pcol = {0.0f, 0.0f, 0.0f, 0.0f}, prow = {0.0f, 0.0f, 0.0f, 0.0f};
    pcol = __builtin_amdgcn_mfma_f32_16x16x32_f16(ones8, lv8, pcol, 0, 0, 0);
    prow = __builtin_amdgcn_mfma_f32_16x16x32_f16(lv8, ones8, prow, 0, 0, 0);
    const int gcol = (int)(pcol[0] * 0.03125f + 0.5f);   // expert-within-16 label

    // ---- in-register softmax + top-2 per token ----
    constexpr float S = 1.0f / 2048.0f;
    #pragma unroll
    for (int r = 0; r < 4; ++r) {
        const int rowl = (int)(prow[r] * 0.03125f + 0.5f);   // token-within-wave label
        const float cv[4] = { acc_hh[0][r] + S * acc_mx[0][r],
                              acc_hh[1][r] + S * acc_mx[1][r],
                              acc_hh[2][r] + S * acc_mx[2][r],
                              acc_hh[3][r] + S * acc_mx[3][r] };
        float a1 = cv[0]; int i1 = gcol;
        float a2 = -3.402823466e+38f; int i2 = 0;
        #pragma unroll
        for (int et = 1; et < 4; ++et) {   // local top2 (idx ascending in et)
            const float v = cv[et]; const int idx = et * 16 + gcol;
            if (v > a1)      { a2 = a1; i2 = i1; a1 = v; i1 = idx; }
            else if (v > a2) { a2 = v; i2 = idx; }
        }
        #pragma unroll
        for (int off = 1; off < 16; off <<= 1) {   // 16-lane top2 merge, tie -> lower idx
            const float b1 = __shfl_xor(a1, off); const int j1 = __shfl_xor(i1, off);
            const float b2 = __shfl_xor(a2, off); const int j2 = __shfl_xor(i2, off);
            const bool bw = (b1 > a1) || (b1 == a1 && j1 < i1);
            const float t1 = bw ? b1 : a1; const int ti1 = bw ? j1 : i1;
            const float lc = bw ? a1 : b1; const int lci = bw ? i1 : j1;
            const float w2 = bw ? b2 : a2; const int wi2 = bw ? j2 : i2;
            const bool dw = (w2 > lc) || (w2 == lc && wi2 < lci);
            a1 = t1; i1 = ti1;
            a2 = dw ? w2 : lc; i2 = dw ? wi2 : lci;
        }
        float Zp = expf(cv[0] - a1) + expf(cv[1] - a1) + expf(cv[2] - a1) + expf(cv[3] - a1);
        #pragma unroll
        for (int off = 1; off < 16; off <<= 1) Zp += __shfl_xor(Zp, off);
        if (l15 == 0) {
            const float p1 = 1.0f / Zp;              // exp(v1-v1)/Z
            const float p2 = expf(a2 - a1) / Zp;
            const float wden = p1 + p2 + 1e-9f;
            const size_t t = (size_t)(tok0 + wid * 16 + rowl);
            out[t * 2 + 0] = p1 / wden;
            out[t * 2 + 1] = p2 / wden;
            out[(size_t)T * 2 + t * 2 + 0] = (float)i1;
            out[(size_t)T * 2 + t * 2 + 1] = (float)i2;
            atomicAdd(&cnt[i1], 1.0f);  atomicAdd(&sm[i1], p1);
            atomicAdd(&cnt[i2], 1.0f);  atomicAdd(&sm[i2], p2);
        }
    }
    __syncthreads();
    if (tid < E) {
        atomicAdd(&gcnt[tid], cnt[tid]);   // device-scope (G12)
        atomicAdd(&gsum[tid], sm[tid]);
    }
    __syncthreads();   // all global atomics drained before done-bump

    // last-finishing block computes the aux loss inline (proven in round 9)
    if (tid == 0) {
        __threadfence();
        const unsigned v = atomicAdd(dcnt, 1u);
        sLast = (v == (unsigned)(gridDim.x - 1)) ? 1u : 0u;
    }
    __syncthreads();
    if (sLast != 0u && tid < E) {
        const float cvn = atomicAdd(&gcnt[tid], 0.0f);   // coherent RMW read
        const float svn = atomicAdd(&gsum[tid], 0.0f);
        const float frac = cvn / ((float)(2 * T) + 1e-6f);
        const float avg  = svn / fmaxf(cvn, 1e-6f);
        float term = frac * avg;
        #pragma unroll
        for (int off = 32; off > 0; off >>= 1)
            term += __shfl_down(term, off);
        if (tid == 0) out[(size_t)T * 4] = term * (float)E;
    }
}

extern "C" void kernel_launch(void* const* d_in, const int* in_sizes, int n_in,
                              void* d_out, int out_size, void* d_ws, size_t ws_size,
                              hipStream_t stream) {
    const float* x = (const float*)d_in[0];
    const float* W = (const float*)d_in[1];
    float* out  = (float*)d_out;
    float* gcnt = (float*)d_ws;                 // 64 floats
    float* gsum = gcnt + E;                     // 64 floats
    unsigned* dcnt = (unsigned*)(gsum + E);     // 1 dword done-counter

    zero_ws_kernel<<<1, 256, 0, stream>>>((float*)d_ws);
    router_kernel<<<T / TOKB, TPB, 0, stream>>>(x, W, out, gcnt, gsum, dcnt);
}